// Round 1
// baseline (568.093 us; speedup 1.0000x reference)
//
#include <hip/hip_runtime.h>
#include <stdint.h>

#define B_   32
#define CIN  128
#define HH   96
#define WW   96
#define HW   (HH*WW)        // 9216
#define NPIX (B_*HW)        // 294912
#define AROWS 144
#define APAD  136           // bf16 elems per row in LDS (272 B, +8 pad)
#define SCALE 0.08838834764831845f  // 1/sqrt(128)

typedef __attribute__((ext_vector_type(8))) short bf16x8;
typedef __attribute__((ext_vector_type(4))) float f32x4;

__device__ inline unsigned short f2bf(float f) {
    unsigned int u = __float_as_uint(f);
    u += 0x7fffu + ((u >> 16) & 1u);   // round-to-nearest-even
    return (unsigned short)(u >> 16);
}

// ---------------- K1: Abuf[144][128] = [W^T W ; v ; 0], vbuf, sbuf ----------
__global__ __launch_bounds__(128) void k1_prep(
    const float* __restrict__ Wm, const float* __restrict__ bias,
    unsigned short* __restrict__ Abuf, float* __restrict__ vbuf,
    float* __restrict__ sbuf) {
    int r = blockIdx.x;      // 0..143
    int c = threadIdx.x;     // 0..127
    float acc = 0.f;
    if (r < 128) {
        for (int f = 0; f < 128; ++f)
            acc += Wm[f * 128 + r] * Wm[f * 128 + c];
    } else if (r == 128) {
        for (int f = 0; f < 128; ++f)
            acc += Wm[f * 128 + c] * bias[f];
        vbuf[c] = acc;
        if (c == 0) {
            float s = 0.f;
            for (int f = 0; f < 128; ++f) s += bias[f] * bias[f];
            sbuf[0] = s;
        }
    }
    Abuf[r * 128 + c] = f2bf(acc);
}

// ---------------- K2: y2[p][c] = M a2 + v (bf16), z2[p] = v.a2 + s ----------
__global__ __launch_bounds__(256) void k2_proj(
    const float* __restrict__ a2, const unsigned short* __restrict__ Abuf,
    const float* __restrict__ vbuf, const float* __restrict__ sbuf,
    unsigned short* __restrict__ y2, float* __restrict__ z2) {
    __shared__ __align__(16) unsigned short Asm[AROWS * APAD];  // 39168 B
    __shared__ __align__(16) unsigned short Bsm[64 * APAD];     // 17408 B

    const int t = threadIdx.x;
    const int bidx = blockIdx.x;
    const int b = bidx / 144;
    const int tile = bidx % 144;
    const int hw0 = tile * 64;

    // stage A (144x128 bf16 = 2304 x 16B)
    for (int i = t; i < 2304; i += 256) {
        int row = i >> 4, seg = i & 15;
        uint4 v = *(const uint4*)(Abuf + row * 128 + seg * 8);
        *(uint4*)(&Asm[row * APAD + seg * 8]) = v;
    }
    // stage B^T: a2 tile 128c x 64px f32 -> Bsm[px][c] bf16
    {
        const int pxq = t & 15;       // pixel quad
        const int ct = t >> 4;        // 0..15
        const float* a2b = a2 + (size_t)b * (CIN * HW);
        for (int cc = ct; cc < 128; cc += 16) {
            float4 f = *(const float4*)(a2b + (size_t)cc * HW + hw0 + pxq * 4);
            Bsm[(pxq * 4 + 0) * APAD + cc] = f2bf(f.x);
            Bsm[(pxq * 4 + 1) * APAD + cc] = f2bf(f.y);
            Bsm[(pxq * 4 + 2) * APAD + cc] = f2bf(f.z);
            Bsm[(pxq * 4 + 3) * APAD + cc] = f2bf(f.w);
        }
    }
    __syncthreads();

    const int wv = t >> 6;
    const int lane = t & 63;
    const int li = lane & 15;
    const int lk = (lane >> 4) * 8;

    f32x4 acc[9];
#pragma unroll
    for (int m = 0; m < 9; ++m) acc[m] = (f32x4){0.f, 0.f, 0.f, 0.f};

#pragma unroll
    for (int kk = 0; kk < 4; ++kk) {
        const int k0 = kk * 32 + lk;
        bf16x8 bfrag = *(const bf16x8*)(&Bsm[(wv * 16 + li) * APAD + k0]);
#pragma unroll
        for (int m = 0; m < 9; ++m) {
            bf16x8 afrag = *(const bf16x8*)(&Asm[(m * 16 + li) * APAD + k0]);
            acc[m] = __builtin_amdgcn_mfma_f32_16x16x32_bf16(afrag, bfrag, acc[m], 0, 0, 0);
        }
    }

    // epilogue: D row = c_out, col = pixel. lane holds 4 consecutive c_out.
    const int px = hw0 + wv * 16 + li;
    const int rbase = (lane >> 4) * 4;
    const size_t pbase = ((size_t)b * HW + px) * 128;
#pragma unroll
    for (int m = 0; m < 8; ++m) {
        int c0 = m * 16 + rbase;
        ushort4 pk;
        pk.x = f2bf(acc[m].x + vbuf[c0 + 0]);
        pk.y = f2bf(acc[m].y + vbuf[c0 + 1]);
        pk.z = f2bf(acc[m].z + vbuf[c0 + 2]);
        pk.w = f2bf(acc[m].w + vbuf[c0 + 3]);
        *(ushort4*)(y2 + pbase + c0) = pk;
    }
    if (rbase == 0) {  // row 128 = v.a2; rows 129+ are zero pad
        z2[(size_t)b * HW + px] = acc[8].x + sbuf[0];
    }
}

// ---------------- K3: correlation, 81 shifts per thread --------------------
__global__ __launch_bounds__(192) void k3_corr(
    const float* __restrict__ x1, const unsigned short* __restrict__ y2,
    const float* __restrict__ z2, float* __restrict__ out) {
    __shared__ __align__(16) unsigned short Ys[10 * 104 * 8];  // 16640 B
    __shared__ float Zs[10 * 104];                             // 4160 B

    const int t = threadIdx.x;
    const int h0 = blockIdx.x * 2;
    const int b = blockIdx.y;
    const int row = t / 96;
    const int w = t - row * 96;
    const int h = h0 + row;

    // stage z2 halo tile once
    for (int cell = t; cell < 1040; cell += 192) {
        int r = cell / 104, wi = cell - r * 104;
        int hs = h0 - 4 + r, wsx = wi - 4;
        float zv = 0.f;
        if (hs >= 0 && hs < HH && wsx >= 0 && wsx < WW)
            zv = z2[(size_t)b * HW + hs * WW + wsx];
        Zs[cell] = zv;
    }

    float acc[81];
#pragma unroll
    for (int s = 0; s < 81; ++s) acc[s] = 0.f;

    const float* x1b = x1 + (size_t)b * (CIN * HW) + h * WW + w;

    for (int ch = 0; ch < 16; ++ch) {
        __syncthreads();
        // stage y2 chunk: 10 rows x 104 w' x 8 channels (16 B per cell)
        for (int cell = t; cell < 1040; cell += 192) {
            int r = cell / 104, wi = cell - r * 104;
            int hs = h0 - 4 + r, wsx = wi - 4;
            uint4 v = make_uint4(0u, 0u, 0u, 0u);
            if (hs >= 0 && hs < HH && wsx >= 0 && wsx < WW)
                v = *(const uint4*)(y2 + (((size_t)b * HW + hs * WW + wsx) * 128 + ch * 8));
            *(uint4*)(&Ys[cell * 8]) = v;
        }
        __syncthreads();

        float xv[8];
#pragma unroll
        for (int i = 0; i < 8; ++i)
            xv[i] = x1b[(size_t)(ch * 8 + i) * HW];

#pragma unroll
        for (int di = 0; di < 9; ++di) {
            const unsigned short* rp = &Ys[((row + di) * 104 + w) * 8];
#pragma unroll
            for (int dj = 0; dj < 9; ++dj) {
                uint4 v = *(const uint4*)(rp + dj * 8);
                float a = acc[di * 9 + dj];
                a += xv[0] * __uint_as_float(v.x << 16);
                a += xv[1] * __uint_as_float(v.x & 0xffff0000u);
                a += xv[2] * __uint_as_float(v.y << 16);
                a += xv[3] * __uint_as_float(v.y & 0xffff0000u);
                a += xv[4] * __uint_as_float(v.z << 16);
                a += xv[5] * __uint_as_float(v.z & 0xffff0000u);
                a += xv[6] * __uint_as_float(v.w << 16);
                a += xv[7] * __uint_as_float(v.w & 0xffff0000u);
                acc[di * 9 + dj] = a;
            }
        }
    }

    const size_t obase = (size_t)b * 81 * HW + h * WW + w;
#pragma unroll
    for (int di = 0; di < 9; ++di) {
#pragma unroll
        for (int dj = 0; dj < 9; ++dj) {
            int s = di * 9 + dj;
            out[obase + (size_t)s * HW] =
                (acc[s] + Zs[(row + di) * 104 + w + dj]) * SCALE;
        }
    }
}

// ---------------- host ------------------------------------------------------
extern "C" void kernel_launch(void* const* d_in, const int* in_sizes, int n_in,
                              void* d_out, int out_size, void* d_ws, size_t ws_size,
                              hipStream_t stream) {
    const float* input1 = (const float*)d_in[0];
    const float* input2 = (const float*)d_in[1];
    const float* proj_w = (const float*)d_in[2];
    const float* proj_b = (const float*)d_in[3];
    float* out = (float*)d_out;

    char* ws = (char*)d_ws;
    const size_t AB_OFF = 0;                      // 144*128*2 = 36864
    const size_t V_OFF  = 36864;                  // 512
    const size_t S_OFF  = 37376;                  // 4
    const size_t Y2_OFF = 40960;                  // 294912*128*2 = 75497472
    const size_t Z2_OFF = Y2_OFF + 75497472ull;   // 294912*4
    const size_t NEED   = Z2_OFF + 1179648ull;
    if (ws_size < NEED) return;  // fail loudly (output stays poisoned)

    unsigned short* Abuf = (unsigned short*)(ws + AB_OFF);
    float* vbuf = (float*)(ws + V_OFF);
    float* sbuf = (float*)(ws + S_OFF);
    unsigned short* y2 = (unsigned short*)(ws + Y2_OFF);
    float* z2 = (float*)(ws + Z2_OFF);

    k1_prep<<<dim3(144), dim3(128), 0, stream>>>(proj_w, proj_b, Abuf, vbuf, sbuf);
    k2_proj<<<dim3(32 * 144), dim3(256), 0, stream>>>(input2, Abuf, vbuf, sbuf, y2, z2);
    k3_corr<<<dim3(48, 32), dim3(192), 0, stream>>>(input1, y2, z2, out);
}

// Round 2
// 315.975 us; speedup vs baseline: 1.7979x; 1.7979x over previous
//
#include <hip/hip_runtime.h>
#include <stdint.h>

#define B_   32
#define CIN  128
#define HH   96
#define WW   96
#define HW   (HH*WW)        // 9216
#define NPIX (B_*HW)        // 294912
#define AROWS 144
#define APAD  136           // bf16 elems per row in LDS (272 B, +8 pad)
#define SCALE 0.08838834764831845f  // 1/sqrt(128)
#define SEGQ  936           // 9 rows * 104 sx, cells per seg plane
#define ESW   100           // epilogue tile row stride (bank-spread)

typedef __attribute__((ext_vector_type(8))) short bf16x8;
typedef __attribute__((ext_vector_type(4))) float f32x4;

__device__ inline unsigned short f2bf(float f) {
    unsigned int u = __float_as_uint(f);
    u += 0x7fffu + ((u >> 16) & 1u);   // round-to-nearest-even
    return (unsigned short)(u >> 16);
}

// ---------------- K1: Abuf[144][128] = [W^T W ; v ; 0], vbuf, sbuf ----------
__global__ __launch_bounds__(128) void k1_prep(
    const float* __restrict__ Wm, const float* __restrict__ bias,
    unsigned short* __restrict__ Abuf, float* __restrict__ vbuf,
    float* __restrict__ sbuf) {
    int r = blockIdx.x;      // 0..143
    int c = threadIdx.x;     // 0..127
    float acc = 0.f;
    if (r < 128) {
        for (int f = 0; f < 128; ++f)
            acc += Wm[f * 128 + r] * Wm[f * 128 + c];
    } else if (r == 128) {
        for (int f = 0; f < 128; ++f)
            acc += Wm[f * 128 + c] * bias[f];
        vbuf[c] = acc;
        if (c == 0) {
            float s = 0.f;
            for (int f = 0; f < 128; ++f) s += bias[f] * bias[f];
            sbuf[0] = s;
        }
    }
    Abuf[r * 128 + c] = f2bf(acc);
}

// ---- K2: y2[seg][b][h][w][8ch] = (M a2 + v) bf16 (planar), z2 = v.a2 + s ---
__global__ __launch_bounds__(256) void k2_proj(
    const float* __restrict__ a2, const unsigned short* __restrict__ Abuf,
    const float* __restrict__ vbuf, const float* __restrict__ sbuf,
    unsigned short* __restrict__ y2, float* __restrict__ z2) {
    __shared__ __align__(16) unsigned short Asm[AROWS * APAD];  // 39168 B
    __shared__ __align__(16) unsigned short Bsm[64 * APAD];     // 17408 B

    const int t = threadIdx.x;
    const int bidx = blockIdx.x;
    const int b = bidx / 144;
    const int tile = bidx % 144;
    const int hw0 = tile * 64;

    // stage A (144x128 bf16 = 2304 x 16B)
    for (int i = t; i < 2304; i += 256) {
        int row = i >> 4, seg = i & 15;
        uint4 v = *(const uint4*)(Abuf + row * 128 + seg * 8);
        *(uint4*)(&Asm[row * APAD + seg * 8]) = v;
    }
    // stage B^T: a2 tile 128c x 64px f32 -> Bsm[px][c] bf16
    {
        const int pxq = t & 15;       // pixel quad
        const int ct = t >> 4;        // 0..15
        const float* a2b = a2 + (size_t)b * (CIN * HW);
        for (int cc = ct; cc < 128; cc += 16) {
            float4 f = *(const float4*)(a2b + (size_t)cc * HW + hw0 + pxq * 4);
            Bsm[(pxq * 4 + 0) * APAD + cc] = f2bf(f.x);
            Bsm[(pxq * 4 + 1) * APAD + cc] = f2bf(f.y);
            Bsm[(pxq * 4 + 2) * APAD + cc] = f2bf(f.z);
            Bsm[(pxq * 4 + 3) * APAD + cc] = f2bf(f.w);
        }
    }
    __syncthreads();

    const int wv = t >> 6;
    const int lane = t & 63;
    const int li = lane & 15;
    const int lk = (lane >> 4) * 8;

    f32x4 acc[9];
#pragma unroll
    for (int m = 0; m < 9; ++m) acc[m] = (f32x4){0.f, 0.f, 0.f, 0.f};

#pragma unroll
    for (int kk = 0; kk < 4; ++kk) {
        const int k0 = kk * 32 + lk;
        bf16x8 bfrag = *(const bf16x8*)(&Bsm[(wv * 16 + li) * APAD + k0]);
#pragma unroll
        for (int m = 0; m < 9; ++m) {
            bf16x8 afrag = *(const bf16x8*)(&Asm[(m * 16 + li) * APAD + k0]);
            acc[m] = __builtin_amdgcn_mfma_f32_16x16x32_bf16(afrag, bfrag, acc[m], 0, 0, 0);
        }
    }

    // epilogue: D row = c_out, col = pixel. lane holds 4 consecutive c_out.
    const int px = hw0 + wv * 16 + li;
    const int rbase = (lane >> 4) * 4;
    const size_t pxoff = (size_t)b * HW + px;
#pragma unroll
    for (int m = 0; m < 8; ++m) {
        int c0 = m * 16 + rbase;
        ushort4 pk;
        pk.x = f2bf(acc[m].x + vbuf[c0 + 0]);
        pk.y = f2bf(acc[m].y + vbuf[c0 + 1]);
        pk.z = f2bf(acc[m].z + vbuf[c0 + 2]);
        pk.w = f2bf(acc[m].w + vbuf[c0 + 3]);
        // planar: [seg = c0>>3][b][h][w][8ch]
        *(ushort4*)(y2 + ((size_t)(c0 >> 3) * NPIX + pxoff) * 8 + (c0 & 7)) = pk;
    }
    if (rbase == 0) {  // row 128 = v.a2; rows 129+ are zero pad
        z2[pxoff] = acc[8].x + sbuf[0];
    }
}

// ---------------- K3: MFMA correlation, 1 h-row per block ------------------
// D[i][j] = sum_c x1[w0+i][c] * y2[h+di-4][w0+j-4][c]; band j-i in [0,8]
__global__ __launch_bounds__(256, 2) void k3_corr(
    const float* __restrict__ x1, const unsigned short* __restrict__ y2,
    const float* __restrict__ z2, float* __restrict__ out) {
    // Ys: 4 k-seg planes x 936 cells x 16B = 59904 B ; Zs: 936 f32 = 3744 B
    __shared__ __align__(16) unsigned char smem[59904 + 3744];
    unsigned short* Ys = (unsigned short*)smem;
    float* Zs = (float*)(smem + 59904);
    float* Es = (float*)smem;            // epilogue alias (9*ESW f32 = 3600 B)

    const int t = threadIdx.x;
    const int bx = blockIdx.x;                 // 0..95
    const int b = blockIdx.y;
    const int h = (bx & 7) * 12 + (bx >> 3);   // XCD-chunked row swizzle (bijective)

    const int wv = t >> 6;       // wave 0..3
    const int l = t & 63;
    const int li = l & 15;       // j (B px) / i-col selector
    const int hi = l >> 4;       // k-seg selector 0..3

    // per-thread staging precompute: 4 rounds cover 936 cells
    int actv[4], goff[4], cellb[4];
#pragma unroll
    for (int q = 0; q < 4; ++q) {
        int cell = t + q * 256;
        int r = cell / 104;
        int sx = cell - r * 104;
        int hs = h - 4 + r, ws = sx - 4;
        actv[q] = (cell < SEGQ);
        goff[q] = (actv[q] && (unsigned)hs < 96u && (unsigned)ws < 96u)
                      ? (hs * 96 + ws) : -1;
        cellb[q] = cell;
    }

    // stage Zs once
#pragma unroll
    for (int q = 0; q < 4; ++q) {
        if (actv[q])
            Zs[cellb[q]] = (goff[q] >= 0) ? z2[(size_t)b * HW + goff[q]] : 0.f;
    }

    f32x4 acc[3][9];
#pragma unroll
    for (int g = 0; g < 3; ++g)
#pragma unroll
        for (int di = 0; di < 9; ++di)
            acc[g][di] = (f32x4){0.f, 0.f, 0.f, 0.f};

    const float* x1b = x1 + (size_t)b * (CIN * HW) + (size_t)h * WW;

    for (int cc = 0; cc < 4; ++cc) {
        // A-frags from global x1 (f32 -> bf16), before barrier to overlap
        bf16x8 afrag[3];
        const int c0 = cc * 32 + hi * 8;
#pragma unroll
        for (int g = 0; g < 3; ++g) {
            const int px = (wv * 3 + g) * 8 + li;
            union { bf16x8 v; unsigned short s[8]; } u;
            if (px < WW) {
#pragma unroll
                for (int q = 0; q < 8; ++q)
                    u.s[q] = f2bf(x1b[(size_t)(c0 + q) * HW + px]);
            } else {
#pragma unroll
                for (int q = 0; q < 8; ++q) u.s[q] = 0;
            }
            afrag[g] = u.v;
        }

        if (cc) __syncthreads();   // protect Ys vs previous MFMA reads
        // stage Ys: 4 seg planes, coalesced 16B cells
#pragma unroll
        for (int seg = 0; seg < 4; ++seg) {
            const size_t pbase = ((size_t)(cc * 4 + seg) * NPIX + (size_t)b * HW) * 8;
#pragma unroll
            for (int q = 0; q < 4; ++q) {
                if (!actv[q]) continue;
                uint4 v = make_uint4(0u, 0u, 0u, 0u);
                if (goff[q] >= 0)
                    v = *(const uint4*)(y2 + pbase + (size_t)goff[q] * 8);
                *(uint4*)(Ys + ((size_t)seg * SEGQ + cellb[q]) * 8) = v;
            }
        }
        __syncthreads();

        // MFMA: 3 units x 9 di
#pragma unroll
        for (int g = 0; g < 3; ++g) {
            const int sxb = (wv * 3 + g) * 8 + li;
#pragma unroll
            for (int di = 0; di < 9; ++di) {
                bf16x8 bfrag = *(const bf16x8*)(Ys + ((hi * 9 + di) * 104 + sxb) * 8);
                acc[g][di] = __builtin_amdgcn_mfma_f32_16x16x32_bf16(
                    afrag[g], bfrag, acc[g][di], 0, 0, 0);
            }
        }
    }

    __syncthreads();  // Ys -> Es alias transition

    // epilogue: extract band, add z-term, coalesced store via Es
#pragma unroll
    for (int di = 0; di < 9; ++di) {
        if (l < 32) {   // only lanes holding valid rows i<8
#pragma unroll
            for (int g = 0; g < 3; ++g) {
                const int uu = wv * 3 + g;
                const float zv = Zs[di * 104 + uu * 8 + li];
#pragma unroll
                for (int reg = 0; reg < 4; ++reg) {
                    const int i = hi * 4 + reg;       // hi in {0,1}
                    const int dji = li - i;
                    if (dji >= 0 && dji <= 8) {
                        Es[dji * ESW + uu * 8 + i] =
                            (acc[g][di][reg] + zv) * SCALE;
                    }
                }
            }
        }
        __syncthreads();
        for (int idx = t; idx < 9 * WW; idx += 256) {
            int dj = idx / WW, w = idx - dj * WW;
            out[((size_t)b * 81 + di * 9 + dj) * HW + (size_t)h * WW + w] =
                Es[dj * ESW + w];
        }
        __syncthreads();
    }
}

// ---------------- host ------------------------------------------------------
extern "C" void kernel_launch(void* const* d_in, const int* in_sizes, int n_in,
                              void* d_out, int out_size, void* d_ws, size_t ws_size,
                              hipStream_t stream) {
    const float* input1 = (const float*)d_in[0];
    const float* input2 = (const float*)d_in[1];
    const float* proj_w = (const float*)d_in[2];
    const float* proj_b = (const float*)d_in[3];
    float* out = (float*)d_out;

    char* ws = (char*)d_ws;
    const size_t AB_OFF = 0;                      // 144*128*2 = 36864
    const size_t V_OFF  = 36864;                  // 512
    const size_t S_OFF  = 37376;                  // 4
    const size_t Y2_OFF = 40960;                  // 294912*128*2 = 75497472
    const size_t Z2_OFF = Y2_OFF + 75497472ull;   // 294912*4
    const size_t NEED   = Z2_OFF + 1179648ull;
    if (ws_size < NEED) return;  // fail loudly (output stays poisoned)

    unsigned short* Abuf = (unsigned short*)(ws + AB_OFF);
    float* vbuf = (float*)(ws + V_OFF);
    float* sbuf = (float*)(ws + S_OFF);
    unsigned short* y2 = (unsigned short*)(ws + Y2_OFF);
    float* z2 = (float*)(ws + Z2_OFF);

    k1_prep<<<dim3(144), dim3(128), 0, stream>>>(proj_w, proj_b, Abuf, vbuf, sbuf);
    k2_proj<<<dim3(32 * 144), dim3(256), 0, stream>>>(input2, Abuf, vbuf, sbuf, y2, z2);
    k3_corr<<<dim3(96, 32), dim3(256), 0, stream>>>(input1, y2, z2, out);
}

// Round 3
// 307.337 us; speedup vs baseline: 1.8484x; 1.0281x over previous
//
#include <hip/hip_runtime.h>
#include <stdint.h>

#define B_   32
#define CIN  128
#define HH   96
#define WW   96
#define HW   (HH*WW)        // 9216
#define NPIX (B_*HW)        // 294912
#define AROWS 144
#define APAD  136           // bf16 elems per row in LDS (272 B, +8 pad)
#define SCALE 0.08838834764831845f  // 1/sqrt(128)
#define ESW   100           // epilogue tile row stride (bank-spread)

typedef __attribute__((ext_vector_type(8))) short bf16x8;
typedef __attribute__((ext_vector_type(4))) float f32x4;

__device__ inline unsigned short f2bf(float f) {
    unsigned int u = __float_as_uint(f);
    u += 0x7fffu + ((u >> 16) & 1u);   // round-to-nearest-even
    return (unsigned short)(u >> 16);
}

// ---------------- K1: Abuf[144][128] = [W^T W ; v ; 0], vbuf, sbuf ----------
__global__ __launch_bounds__(128) void k1_prep(
    const float* __restrict__ Wm, const float* __restrict__ bias,
    unsigned short* __restrict__ Abuf, float* __restrict__ vbuf,
    float* __restrict__ sbuf) {
    int r = blockIdx.x;      // 0..143
    int c = threadIdx.x;     // 0..127
    float acc = 0.f;
    if (r < 128) {
        for (int f = 0; f < 128; ++f)
            acc += Wm[f * 128 + r] * Wm[f * 128 + c];
    } else if (r == 128) {
        for (int f = 0; f < 128; ++f)
            acc += Wm[f * 128 + c] * bias[f];
        vbuf[c] = acc;
        if (c == 0) {
            float s = 0.f;
            for (int f = 0; f < 128; ++f) s += bias[f] * bias[f];
            sbuf[0] = s;
        }
    }
    Abuf[r * 128 + c] = f2bf(acc);
}

// ---- K2: y2[seg][b][hw][8ch] = (M a2 + v) bf16 planar; z2 = v.a2 + s; -----
// ---- phase 0: y1[seg][b][hw][8ch] = bf16(a1) planar (pure cast+relayout) --
__global__ __launch_bounds__(256) void k2_projcast(
    const float* __restrict__ a2, const float* __restrict__ a1,
    const unsigned short* __restrict__ Abuf,
    const float* __restrict__ vbuf, const float* __restrict__ sbuf,
    unsigned short* __restrict__ y2, float* __restrict__ z2,
    unsigned short* __restrict__ y1) {
    __shared__ __align__(16) unsigned short Asm[AROWS * APAD];  // 39168 B
    __shared__ __align__(16) unsigned short Bsm[64 * APAD];     // 17408 B

    const int t = threadIdx.x;
    const int bidx = blockIdx.x;
    const int b = bidx / 144;
    const int tile = bidx % 144;
    const int hw0 = tile * 64;

    const int pxq = t & 15;       // pixel quad
    const int ct = t >> 4;        // 0..15

    // ---- phase 0: input1 tile -> Csm (aliases Asm) -> y1 planar ----
    {
        unsigned short* Csm = Asm;
        const float* a1b = a1 + (size_t)b * (CIN * HW);
        for (int cc = ct; cc < 128; cc += 16) {
            float4 f = *(const float4*)(a1b + (size_t)cc * HW + hw0 + pxq * 4);
            Csm[(pxq * 4 + 0) * APAD + cc] = f2bf(f.x);
            Csm[(pxq * 4 + 1) * APAD + cc] = f2bf(f.y);
            Csm[(pxq * 4 + 2) * APAD + cc] = f2bf(f.z);
            Csm[(pxq * 4 + 3) * APAD + cc] = f2bf(f.w);
        }
        __syncthreads();
#pragma unroll
        for (int k = 0; k < 4; ++k) {
            int i = t + k * 256;          // 0..1023
            int px = i & 63, sg = i >> 6; // sg 0..15
            uint4 v = *(const uint4*)(&Csm[px * APAD + sg * 8]);
            *(uint4*)(y1 + ((size_t)sg * NPIX + (size_t)b * HW + hw0 + px) * 8) = v;
        }
        __syncthreads();   // Csm reads done before Asm overwrite
    }

    // ---- phase 1: stage A (144x128 bf16) and B^T tile ----
    for (int i = t; i < 2304; i += 256) {
        int row = i >> 4, seg = i & 15;
        uint4 v = *(const uint4*)(Abuf + row * 128 + seg * 8);
        *(uint4*)(&Asm[row * APAD + seg * 8]) = v;
    }
    {
        const float* a2b = a2 + (size_t)b * (CIN * HW);
        for (int cc = ct; cc < 128; cc += 16) {
            float4 f = *(const float4*)(a2b + (size_t)cc * HW + hw0 + pxq * 4);
            Bsm[(pxq * 4 + 0) * APAD + cc] = f2bf(f.x);
            Bsm[(pxq * 4 + 1) * APAD + cc] = f2bf(f.y);
            Bsm[(pxq * 4 + 2) * APAD + cc] = f2bf(f.z);
            Bsm[(pxq * 4 + 3) * APAD + cc] = f2bf(f.w);
        }
    }
    __syncthreads();

    const int wv = t >> 6;
    const int lane = t & 63;
    const int li = lane & 15;
    const int lk = (lane >> 4) * 8;

    f32x4 acc[9];
#pragma unroll
    for (int m = 0; m < 9; ++m) acc[m] = (f32x4){0.f, 0.f, 0.f, 0.f};

#pragma unroll
    for (int kk = 0; kk < 4; ++kk) {
        const int k0 = kk * 32 + lk;
        bf16x8 bfrag = *(const bf16x8*)(&Bsm[(wv * 16 + li) * APAD + k0]);
#pragma unroll
        for (int m = 0; m < 9; ++m) {
            bf16x8 afrag = *(const bf16x8*)(&Asm[(m * 16 + li) * APAD + k0]);
            acc[m] = __builtin_amdgcn_mfma_f32_16x16x32_bf16(afrag, bfrag, acc[m], 0, 0, 0);
        }
    }

    // epilogue: D row = c_out, col = pixel. lane holds 4 consecutive c_out.
    const int px = hw0 + wv * 16 + li;
    const int rbase = (lane >> 4) * 4;
    const size_t pxoff = (size_t)b * HW + px;
#pragma unroll
    for (int m = 0; m < 8; ++m) {
        int c0 = m * 16 + rbase;
        ushort4 pk;
        pk.x = f2bf(acc[m].x + vbuf[c0 + 0]);
        pk.y = f2bf(acc[m].y + vbuf[c0 + 1]);
        pk.z = f2bf(acc[m].z + vbuf[c0 + 2]);
        pk.w = f2bf(acc[m].w + vbuf[c0 + 3]);
        // planar: [seg = c0>>3][b][hw][8ch]
        *(ushort4*)(y2 + ((size_t)(c0 >> 3) * NPIX + pxoff) * 8 + (c0 & 7)) = pk;
    }
    if (rbase == 0) {  // row 128 = v.a2; rows 129+ are zero pad
        z2[pxoff] = acc[8].x + sbuf[0];
    }
}

// ---------------- K3: MFMA correlation, barrier-free main loop -------------
// D[i][j] = sum_c y1[h][u8+i][c] * y2[h+di-4][u8+j-4][c]; band j-i in [0,8]
__global__ __launch_bounds__(256) void k3_corr(
    const unsigned short* __restrict__ y1, const unsigned short* __restrict__ y2,
    const float* __restrict__ z2, float* __restrict__ out) {
    __shared__ float Zs[9 * 104];        // 3744 B
    __shared__ float Es[81 * ESW];       // 32400 B

    const int t = threadIdx.x;
    const int bx = blockIdx.x;                 // 0..95
    const int b = blockIdx.y;
    const int h = (bx & 7) * 12 + (bx >> 3);   // XCD-chunked row swizzle (bijective)

    const int wv = t >> 6;       // wave 0..3
    const int l = t & 63;
    const int li = l & 15;       // fragment row/col selector
    const int hi = l >> 4;       // k-seg selector 0..3

    // stage z-term halo (read in band-extract after the barrier below)
    for (int cell = t; cell < 936; cell += 256) {
        int r = cell / 104, sx = cell - r * 104;
        int hs = h - 4 + r, wsx = sx - 4;
        float zv = 0.f;
        if ((unsigned)hs < 96u && (unsigned)wsx < 96u)
            zv = z2[(size_t)b * HW + hs * 96 + wsx];
        Zs[cell] = zv;
    }

    // A-frags: 12 coalesced 16B loads from y1 planar, held in registers
    bf16x8 afr[3][4];
#pragma unroll
    for (int g = 0; g < 3; ++g) {
        const int px = (wv * 3 + g) * 8 + li;
#pragma unroll
        for (int cc = 0; cc < 4; ++cc) {
            uint4 v = make_uint4(0u, 0u, 0u, 0u);
            if (px < 96)
                v = *(const uint4*)(y1 +
                    ((size_t)(cc * 4 + hi) * NPIX + (size_t)b * HW + (size_t)h * 96 + px) * 8);
            union { uint4 u; bf16x8 f; } cv; cv.u = v;
            afr[g][cc] = cv.f;
        }
    }
    __syncthreads();   // Zs ready

    for (int di = 0; di < 9; ++di) {
        const int hs = h - 4 + di;
        const bool rowok = ((unsigned)hs < 96u);
        const long rb = ((long)b * HW + (long)hs * 96) * 8;

        f32x4 ac[3];
#pragma unroll
        for (int g = 0; g < 3; ++g) ac[g] = (f32x4){0.f, 0.f, 0.f, 0.f};

#pragma unroll
        for (int cc = 0; cc < 4; ++cc) {
            const long sb = (long)(cc * 4 + hi) * NPIX * 8 + rb;
#pragma unroll
            for (int g = 0; g < 3; ++g) {
                const int pxj = (wv * 3 + g) * 8 + li - 4;
                uint4 v = make_uint4(0u, 0u, 0u, 0u);
                if (rowok && (unsigned)pxj < 96u)
                    v = *(const uint4*)(y2 + sb + (long)pxj * 8);
                union { uint4 u; bf16x8 f; } cv; cv.u = v;
                ac[g] = __builtin_amdgcn_mfma_f32_16x16x32_bf16(
                    afr[g][cc], cv.f, ac[g], 0, 0, 0);
            }
        }

        // band extract into Es (no barrier; each cell written exactly once)
        if (l < 32) {
#pragma unroll
            for (int g = 0; g < 3; ++g) {
                const int uu = wv * 3 + g;
                const float zv = Zs[di * 104 + uu * 8 + li];
#pragma unroll
                for (int reg = 0; reg < 4; ++reg) {
                    const int i = hi * 4 + reg;     // hi in {0,1} -> i 0..7
                    const int dji = li - i;
                    if (dji >= 0 && dji <= 8)
                        Es[(di * 9 + dji) * ESW + uu * 8 + i] =
                            (ac[g][reg] + zv) * SCALE;
                }
            }
        }
    }

    __syncthreads();
    // bulk coalesced store: 81 shift-planes x 96 w
    const size_t ob = (size_t)b * 81 * HW + (size_t)h * 96;
    for (int idx = t; idx < 81 * 96; idx += 256) {
        int s = idx / 96, w = idx - s * 96;
        out[ob + (size_t)s * HW + w] = Es[s * ESW + w];
    }
}

// ---------------- host ------------------------------------------------------
extern "C" void kernel_launch(void* const* d_in, const int* in_sizes, int n_in,
                              void* d_out, int out_size, void* d_ws, size_t ws_size,
                              hipStream_t stream) {
    const float* input1 = (const float*)d_in[0];
    const float* input2 = (const float*)d_in[1];
    const float* proj_w = (const float*)d_in[2];
    const float* proj_b = (const float*)d_in[3];
    float* out = (float*)d_out;

    char* ws = (char*)d_ws;
    const size_t AB_OFF = 0;                      // 144*128*2 = 36864
    const size_t V_OFF  = 36864;                  // 512
    const size_t S_OFF  = 37376;                  // 4
    const size_t Y2_OFF = 40960;                  // 294912*128*2 = 75497472
    const size_t Z2_OFF = Y2_OFF + 75497472ull;   // 294912*4 = 1179648
    const size_t Y1_OFF = Z2_OFF + 1179648ull;
    const size_t NEED   = Y1_OFF + 75497472ull;   // ~145 MB
    if (ws_size < NEED) return;  // fail loudly (output stays poisoned)

    unsigned short* Abuf = (unsigned short*)(ws + AB_OFF);
    float* vbuf = (float*)(ws + V_OFF);
    float* sbuf = (float*)(ws + S_OFF);
    unsigned short* y2 = (unsigned short*)(ws + Y2_OFF);
    float* z2 = (float*)(ws + Z2_OFF);
    unsigned short* y1 = (unsigned short*)(ws + Y1_OFF);

    k1_prep<<<dim3(144), dim3(128), 0, stream>>>(proj_w, proj_b, Abuf, vbuf, sbuf);
    k2_projcast<<<dim3(32 * 144), dim3(256), 0, stream>>>(
        input2, input1, Abuf, vbuf, sbuf, y2, z2, y1);
    k3_corr<<<dim3(96, 32), dim3(256), 0, stream>>>(y1, y2, z2, out);
}